// Round 1
// 185.241 us; speedup vs baseline: 1.0662x; 1.0662x over previous
//
#include <hip/hip_runtime.h>

#define NFRAMES 3749   // (960000-512)/256 + 1
#define NBLOCKS 3750   // 256-sample hop blocks per batch (960000/256)
#define NSAMP   960000
#define NBATCH  32
#define NWORDS  59     // ceil(3750/64) -> covers bit index up to 3775 (incl. e==NFRAMES)
#define SILENCE_FRAMES 18
#define MIN_SPEECH_FRAMES 6
#define MAXSEG  256    // true bound: 1 + floor(3748/19) = 198

// Kernel A: fp64 sums of fp32 squares per 256-sample hop block.
// Lane-contiguous float4 loads (1 KiB per wave instruction, fully coalesced);
// instruction i of wave w covers exactly hop block 4i+w -> full-wave reduce.
__global__ __launch_bounds__(256) void vad_block_sums(const float* __restrict__ wav,
                                                      double* __restrict__ bs) {
    int tid = threadIdx.x;
    int w = tid >> 6, lane = tid & 63;
    const float4* q = (const float4*)(wav + (size_t)blockIdx.x * 4096);
    #pragma unroll
    for (int i = 0; i < 4; ++i) {
        float4 v = q[(i << 8) + tid];
        double a = (double)(v.x * v.x) + (double)(v.y * v.y)
                 + (double)(v.z * v.z) + (double)(v.w * v.w);
        #pragma unroll
        for (int m = 1; m < 64; m <<= 1)
            a += __shfl_xor(a, m, 64);
        if (lane == 0)
            bs[(size_t)blockIdx.x * 16 + (i << 2) + w] = a;
    }
}

// Kernel B: one block (512 threads) per batch. Energy bits live in registers
// (static-indexed ub[8], sentinel 0xFFFFFFFF for t >= NFRAMES; all valid
// energies are non-negative floats so (int)u >= 0 <=> valid).
__global__ __launch_bounds__(512) void vad_finish(const double* __restrict__ bs,
                                                  int* __restrict__ out) {
    __shared__ __attribute__((aligned(16))) int hist[4][8][256]; // per-pass, per-wave
    __shared__ unsigned long long mw[NWORDS];   // mask bits
    __shared__ unsigned long long sw[NWORDS];   // segment-start bits
    __shared__ unsigned long long lw[NWORDS];   // segment-last-one bits
    __shared__ unsigned long long Sw[NWORDS];   // valid-segment start markers
    __shared__ unsigned long long Ew[NWORDS];   // valid-segment end markers
    __shared__ int wbS[NWORDS], wbL[NWORDS];    // word-prefix bit counts
    __shared__ int startpos[MAXSEG], lastpos[MAXSEG];
    __shared__ int nzero_sh, nseg_sh;
    __shared__ unsigned sel_prefix_sh;
    __shared__ int sel_k_sh;
    __shared__ int cLE_sh;
    __shared__ unsigned minGT_sh;
    __shared__ float thr_sh;

    int b = blockIdx.x;
    int tid = threadIdx.x;
    int lane = tid & 63, wv = tid >> 6;
    const double* row = bs + (size_t)b * NBLOCKS;

    if (tid == 0) { nzero_sh = 0; sel_prefix_sh = 0u; cLE_sh = 0; minGT_sh = 0xFFFFFFFFu; }
    // zero all 4 pass-histograms once (int4-vectorized, 4 iters/thread)
    #pragma unroll
    for (int i = 0; i < 4; ++i)
        ((int4*)hist)[(i << 9) + tid] = make_int4(0, 0, 0, 0);

    // Phase 1: energies; bits kept in registers (STATIC indexing -> VGPRs).
    unsigned ub[8];
    int myzero = 0;
    #pragma unroll
    for (int i = 0; i < 8; ++i) {
        int t = tid + (i << 9);
        unsigned u = 0xFFFFFFFFu;               // sentinel: (int)u < 0
        if (t < NFRAMES) {
            double s = row[t] + row[t + 1];
            float e = (float)(s * (1.0 / 512.0));
            u = __float_as_uint(e);
            if (e <= 0.0f) myzero++;
        }
        ub[i] = u;
    }
    #pragma unroll
    for (int m = 1; m < 64; m <<= 1)
        myzero += __shfl_xor(myzero, m, 64);
    if (lane == 0 && myzero) atomicAdd(&nzero_sh, myzero);
    __syncthreads();

    int nzero = nzero_sh;
    int nz = NFRAMES - nzero;

    if (nz > 0) {   // block-uniform
        float pos = 0.2f * (float)(nz - 1);
        int lo = (int)floorf(pos), hi = (int)ceilf(pos);
        int rank_lo = min(max(nzero + lo, 0), NFRAMES - 1);
        int rank_hi = min(max(nzero + hi, 0), NFRAMES - 1);
        if (tid == 0) sel_k_sh = rank_lo;       // visible after pass-0 post-atomic sync

        // Phase 2: radix select rank_lo (4 byte passes, MSB first).
        // Wave-aggregated LDS atomics: if all active lanes share a bin
        // (the common case for pass 1 on concentrated data), one add.
        int pno = 0;
        for (int shift = 24; shift >= 0; shift -= 8, ++pno) {
            unsigned pref = sel_prefix_sh;
            unsigned pmask = (shift == 24) ? 0u : (0xFFFFFFFFu << (shift + 8));
            int* hw = hist[pno][wv];
            #pragma unroll
            for (int j = 0; j < 8; ++j) {
                unsigned u = ub[j];
                bool act = ((int)u >= 0) && ((u & pmask) == (pref & pmask));
                unsigned long long ball = __ballot(act);
                if (ball != 0ull) {             // wave-uniform
                    unsigned bin = (u >> shift) & 255u;
                    int leader = (int)__ffsll(ball) - 1;
                    unsigned fbin = (unsigned)__shfl((int)bin, leader, 64);
                    unsigned long long same = __ballot(act && (bin == fbin));
                    if (same == ball) {
                        if (lane == leader) atomicAdd(&hw[fbin], (int)__popcll(ball));
                    } else if (act) {
                        atomicAdd(&hw[bin], 1);
                    }
                }
            }
            __syncthreads();
            if (wv == 0) {
                int bin0 = lane << 2;
                int h0 = 0, h1 = 0, h2 = 0, h3 = 0;
                #pragma unroll
                for (int c = 0; c < 8; ++c) {
                    int4 hc = *(const int4*)&hist[pno][c][bin0];
                    h0 += hc.x; h1 += hc.y; h2 += hc.z; h3 += hc.w;
                }
                int tot = h0 + h1 + h2 + h3;
                int inc = tot;
                #pragma unroll
                for (int off = 1; off < 64; off <<= 1) {
                    int y = __shfl_up(inc, off, 64);
                    if (lane >= off) inc += y;
                }
                int run = inc - tot;            // exclusive prefix of this lane's bins
                int k = sel_k_sh;
                int hh[4] = {h0, h1, h2, h3};
                #pragma unroll
                for (int j2 = 0; j2 < 4; ++j2) {
                    if (k >= run && k < run + hh[j2]) { // exactly one (lane,j2) hits
                        sel_prefix_sh = pref | ((unsigned)(bin0 + j2) << shift);
                        sel_k_sh = k - run;
                    }
                    run += hh[j2];
                }
            }
            __syncthreads();
        }

        unsigned vb = sel_prefix_sh;   // bits of s[rank_lo]

        // Phase 3: derive s[rank_lo + 1] if needed (one reduce pass)
        if (rank_hi != rank_lo) {      // block-uniform
            int c = 0;
            unsigned mg = 0xFFFFFFFFu;
            #pragma unroll
            for (int j = 0; j < 8; ++j) {
                unsigned u = ub[j];
                if ((int)u >= 0) {
                    if (u <= vb) c++;
                    else mg = min(mg, u);
                }
            }
            #pragma unroll
            for (int off = 32; off > 0; off >>= 1) {
                c += __shfl_xor(c, off, 64);
                mg = min(mg, (unsigned)__shfl_xor((int)mg, off, 64));
            }
            if (lane == 0) {
                atomicAdd(&cLE_sh, c);
                atomicMin(&minGT_sh, mg);
            }
            __syncthreads();
        }

        // Phase 4: threshold (fp32 arithmetic exactly as reference)
        if (tid == 0) {
            float vlo = __uint_as_float(vb);
            float vhi;
            if (rank_hi == rank_lo) vhi = vlo;
            else vhi = (cLE_sh >= rank_lo + 2) ? vlo : __uint_as_float(minGT_sh);
            float frac = pos - (float)lo;
            thr_sh = vlo * (1.0f - frac) + vhi * frac;
        }
    } else {
        if (tid == 0) thr_sh = 0.01f;
    }
    __syncthreads();
    float thr = thr_sh;

    // Phase 5: mask bit-words straight from registers.
    // Thread layout t = 64*wv + lane + 512*i  ->  word (wv + 8i), bit = lane.
    #pragma unroll
    for (int i = 0; i < 8; ++i) {
        unsigned u = ub[i];
        bool p = ((int)u >= 0) && (__uint_as_float(u) > thr);
        unsigned long long bm = __ballot(p);
        int wi = wv + (i << 3);
        if (lane == 0 && wi < NWORDS) mw[wi] = bm;
    }
    __syncthreads();

    // Phase 6: segment starts (no 1 in prev 18) / last-ones (no 1 in next 18)
    for (int wi = wv; wi < NWORDS; wi += 8) {
        unsigned long long W  = mw[wi];
        unsigned long long Wm = (wi > 0) ? mw[wi - 1] : 0ull;
        unsigned long long Wp = (wi + 1 < NWORDS) ? mw[wi + 1] : 0ull;
        int l = lane;
        bool mt = (W >> l) & 1ull;
        bool prev_any, next_any;
        if (l >= 18) {
            prev_any = ((W >> (l - 18)) & 0x3FFFFull) != 0ull;
        } else {
            unsigned long long lowpart = W & ((1ull << l) - 1ull);   // bits t-l..t-1
            unsigned long long hipart  = Wm >> (46 + l);             // 18-l bits
            prev_any = (lowpart | hipart) != 0ull;
        }
        if (l <= 45) {
            next_any = ((W >> (l + 1)) & 0x3FFFFull) != 0ull;
        } else {
            unsigned long long a  = (l < 63) ? (W >> (l + 1)) : 0ull; // 63-l bits
            unsigned long long bb = Wp & ((1ull << (l - 45)) - 1ull); // l-45 bits
            next_any = (a | bb) != 0ull;
        }
        unsigned long long bS = __ballot(mt && !prev_any);
        unsigned long long bL = __ballot(mt && !next_any);
        if (lane == 0) { sw[wi] = bS; lw[wi] = bL; }
    }
    __syncthreads();

    // Phase 7: word-prefix counts of starts/lasts via parallel wave scans
    if (wv < 2) {
        const unsigned long long* src = (wv == 0) ? sw : lw;
        unsigned long long w_ = (lane < NWORDS) ? src[lane] : 0ull;
        int c = __popcll(w_);
        int inc = c;
        #pragma unroll
        for (int off = 1; off < 64; off <<= 1) {
            int y = __shfl_up(inc, off, 64);
            if (lane >= off) inc += y;
        }
        int* dst = (wv == 0) ? wbS : wbL;
        if (lane < NWORDS) dst[lane] = inc - c;
        if (wv == 0 && lane == NWORDS - 1) nseg_sh = inc;
    }
    __syncthreads();

    // Phase 8: scatter ordered start/last positions; clear S/E marker words
    for (int wi = wv; wi < NWORDS; wi += 8) {
        unsigned long long wS = sw[wi], wL = lw[wi];
        int t = (wi << 6) + lane;
        unsigned long long lmask = (1ull << lane) - 1ull;
        if ((wS >> lane) & 1ull) startpos[wbS[wi] + __popcll(wS & lmask)] = t;
        if ((wL >> lane) & 1ull) lastpos[wbL[wi] + __popcll(wL & lmask)] = t;
    }
    for (int wi = tid; wi < NWORDS; wi += 512) { Sw[wi] = 0ull; Ew[wi] = 0ull; }
    __syncthreads();

    // Phase 9: per segment: end = L (closed) or n (open, L >= n-18); validity; markers
    int nseg = nseg_sh;
    for (int k = tid; k < nseg; k += 512) {
        int s = startpos[k], L = lastpos[k];
        int e = (L >= NFRAMES - SILENCE_FRAMES) ? NFRAMES : L;
        if (e - s >= MIN_SPEECH_FRAMES) {
            atomicOr(&Sw[s >> 6], 1ull << (s & 63));
            atomicOr(&Ew[e >> 6], 1ull << (e & 63));
        }
    }
    __syncthreads();

    // Phase 10: word-prefix counts of S/E markers via parallel wave scans
    if (wv < 2) {
        const unsigned long long* src = (wv == 0) ? Sw : Ew;
        unsigned long long w_ = (lane < NWORDS) ? src[lane] : 0ull;
        int c = __popcll(w_);
        int inc = c;
        #pragma unroll
        for (int off = 1; off < 64; off <<= 1) {
            int y = __shfl_up(inc, off, 64);
            if (lane >= off) inc += y;
        }
        int* dst = (wv == 0) ? wbS : wbL;
        if (lane < NWORDS) dst[lane] = inc - c;
    }
    __syncthreads();

    // Phase 11: coverage = (#starts <= t) > (#ends <= t); write int32 output
    int* orow = out + (size_t)b * NFRAMES;
    for (int wi = wv; wi < NWORDS; wi += 8) {
        unsigned long long wS2 = Sw[wi], wE2 = Ew[wi];
        int t = (wi << 6) + lane;
        unsigned long long ile = (lane == 63) ? ~0ull : ((1ull << (lane + 1)) - 1ull);
        int cS = wbS[wi] + __popcll(wS2 & ile);
        int cE = wbL[wi] + __popcll(wE2 & ile);
        if (t < NFRAMES) orow[t] = (cS > cE) ? 1 : 0;
    }
}

extern "C" void kernel_launch(void* const* d_in, const int* in_sizes, int n_in,
                              void* d_out, int out_size, void* d_ws, size_t ws_size,
                              hipStream_t stream) {
    const float* wav = (const float*)d_in[0];
    int* out = (int*)d_out;
    double* bs = (double*)d_ws;   // NBATCH*NBLOCKS doubles = 960 KB

    vad_block_sums<<<(NBATCH * NSAMP) / 4096, 256, 0, stream>>>(wav, bs);
    vad_finish<<<NBATCH, 512, 0, stream>>>(bs, out);
}

// Round 2
// 184.038 us; speedup vs baseline: 1.0732x; 1.0065x over previous
//
#include <hip/hip_runtime.h>

#define NFRAMES 3749   // (960000-512)/256 + 1
#define NBLOCKS 3750   // 256-sample hop blocks per batch (960000/256)
#define NSAMP   960000
#define NBATCH  32
#define NWORDS  59     // ceil(3750/64)
#define SILENCE_FRAMES 18
#define MIN_SPEECH_FRAMES 6
#define MAXSEG  256    // true bound: 1 + floor(3748/19) = 198

// Kernel A: fp64 sums of fp32 squares per 256-sample hop block.
// Lane-contiguous float4 loads (1 KiB per wave instruction, fully coalesced);
// instruction i of wave w covers exactly hop block 4i+w -> full-wave reduce.
// At the HBM read roofline (~17.7 us for 122.88 MB) -- unchanged.
__global__ __launch_bounds__(256) void vad_block_sums(const float* __restrict__ wav,
                                                      double* __restrict__ bs) {
    int tid = threadIdx.x;
    int w = tid >> 6, lane = tid & 63;
    const float4* q = (const float4*)(wav + (size_t)blockIdx.x * 4096);
    #pragma unroll
    for (int i = 0; i < 4; ++i) {
        float4 v = q[(i << 8) + tid];
        double a = (double)(v.x * v.x) + (double)(v.y * v.y)
                 + (double)(v.z * v.z) + (double)(v.w * v.w);
        #pragma unroll
        for (int m = 1; m < 64; m <<= 1)
            a += __shfl_xor(a, m, 64);
        if (lane == 0)
            bs[(size_t)blockIdx.x * 16 + (i << 2) + w] = a;
    }
}

// Kernel B: one block (512 threads) per batch. Latency-optimized:
//  - pass-1 histogram accumulated inside the energy loop (pre-sync overlap)
//  - radix select: ONE sync per pass; every wave reduces + selects redundantly
//    in registers (identical integer ops -> block-uniform prefix/k)
//  - phases 6-10 on wave 0 only, shuffle-based, zero internal barriers
//  Total __syncthreads: 8 (was ~16).
__global__ __launch_bounds__(512) void vad_finish(const double* __restrict__ bs,
                                                  int* __restrict__ out) {
    __shared__ __attribute__((aligned(16))) int hist[4][4][256]; // pass, copy, bin (16 KB)
    __shared__ unsigned long long mw[NWORDS];   // mask bits
    __shared__ unsigned long long Sw[NWORDS];   // valid-segment start markers
    __shared__ unsigned long long Ew[NWORDS];   // valid-segment end markers
    __shared__ int wbS[NWORDS], wbL[NWORDS];    // word-prefix marker counts
    __shared__ int startpos[MAXSEG], lastpos[MAXSEG];
    __shared__ int nzero_sh;
    __shared__ int cLE_sh;
    __shared__ unsigned minGT_sh;

    int b = blockIdx.x;
    int tid = threadIdx.x;
    int lane = tid & 63, wv = tid >> 6;
    const double* row = bs + (size_t)b * NBLOCKS;

    // zero all 4 pass-histograms (16 KB -> 2 int4/thread) + scalars
    {
        int4* hz = (int4*)hist;
        hz[tid] = make_int4(0, 0, 0, 0);
        hz[tid + 512] = make_int4(0, 0, 0, 0);
    }
    if (tid == 0) { nzero_sh = 0; cLE_sh = 0; minGT_sh = 0xFFFFFFFFu; }
    __syncthreads();                                   // S0

    // Phase 1: energies (bits -> registers, sentinel 0xFFFFFFFF for t>=NFRAMES),
    // nzero count, AND pass-1 (top byte) histogram -- all before one sync.
    unsigned ub[8];
    int myzero = 0;
    int* h0w = hist[0][wv >> 1];
    #pragma unroll
    for (int i = 0; i < 8; ++i) {
        int t = tid + (i << 9);
        unsigned u = 0xFFFFFFFFu;                      // sentinel: (int)u < 0
        if (t < NFRAMES) {
            double s = row[t] + row[t + 1];
            float e = (float)(s * (1.0 / 512.0));
            u = __float_as_uint(e);
            if (e <= 0.0f) myzero++;
        }
        ub[i] = u;
        // pass-1 aggregated atomic (all-same fast path; data is concentrated)
        bool act = ((int)u >= 0);
        unsigned long long ball = __ballot(act);
        if (ball != 0ull) {
            unsigned bin = u >> 24;
            int leader = (int)__ffsll(ball) - 1;
            unsigned fbin = (unsigned)__shfl((int)bin, leader, 64);
            unsigned long long same = __ballot(act && (bin == fbin));
            if (same == ball) {
                if (lane == leader) atomicAdd(&h0w[fbin], (int)__popcll(ball));
            } else if (act) {
                atomicAdd(&h0w[bin], 1);
            }
        }
    }
    #pragma unroll
    for (int m = 1; m < 64; m <<= 1)
        myzero += __shfl_xor(myzero, m, 64);
    if (lane == 0 && myzero) atomicAdd(&nzero_sh, myzero);
    __syncthreads();                                   // S1

    int nzero = nzero_sh;
    int nz = NFRAMES - nzero;
    float thr;

    if (nz > 0) {   // block-uniform
        float pos = 0.2f * (float)(nz - 1);
        int lo = (int)floorf(pos), hi = (int)ceilf(pos);
        int rank_lo = min(max(nzero + lo, 0), NFRAMES - 1);
        int rank_hi = min(max(nzero + hi, 0), NFRAMES - 1);

        unsigned pref = 0u;   // selection prefix (register, block-uniform)
        int k = rank_lo;      // remaining rank (register, block-uniform)

        // Radix select: 4 MSB-first byte passes, ONE sync each.
        #pragma unroll
        for (int p = 0; p < 4; ++p) {
            int shift = 24 - (p << 3);
            if (p > 0) {
                unsigned pmask = 0xFFFFFFFFu << (shift + 8);
                int* hw = hist[p][wv >> 1];
                #pragma unroll
                for (int j = 0; j < 8; ++j) {
                    unsigned u = ub[j];
                    bool act = ((int)u >= 0) && ((u & pmask) == (pref & pmask));
                    unsigned long long ball = __ballot(act);
                    if (ball != 0ull) {
                        unsigned bin = (u >> shift) & 255u;
                        int leader = (int)__ffsll(ball) - 1;
                        unsigned fbin = (unsigned)__shfl((int)bin, leader, 64);
                        unsigned long long same = __ballot(act && (bin == fbin));
                        if (same == ball) {
                            if (lane == leader) atomicAdd(&hw[fbin], (int)__popcll(ball));
                        } else if (act) {
                            atomicAdd(&hw[bin], 1);
                        }
                    }
                }
                __syncthreads();                       // S2 / S3 / S4
            }
            // redundant reduce + select: EVERY wave, identical -> block-uniform
            int bin0 = lane << 2;
            int4 a0 = *(const int4*)&hist[p][0][bin0];
            int4 a1 = *(const int4*)&hist[p][1][bin0];
            int4 a2 = *(const int4*)&hist[p][2][bin0];
            int4 a3 = *(const int4*)&hist[p][3][bin0];
            int h[4] = { a0.x + a1.x + a2.x + a3.x, a0.y + a1.y + a2.y + a3.y,
                         a0.z + a1.z + a2.z + a3.z, a0.w + a1.w + a2.w + a3.w };
            int tot = h[0] + h[1] + h[2] + h[3];
            int inc = tot;
            #pragma unroll
            for (int off = 1; off < 64; off <<= 1) {
                int y = __shfl_up(inc, off, 64);
                if (lane >= off) inc += y;
            }
            int run = inc - tot;                       // exclusive prefix of lane's bins
            unsigned my_pref = 0u; int my_k = 0; bool found = false;
            #pragma unroll
            for (int j2 = 0; j2 < 4; ++j2) {
                if (!found && k >= run && k < run + h[j2]) { // exactly one (lane,j2) hits
                    my_pref = pref | ((unsigned)(bin0 + j2) << shift);
                    my_k = k - run;
                    found = true;
                }
                run += h[j2];
            }
            unsigned long long fb = __ballot(found);
            int leader = (int)__ffsll(fb) - 1;
            pref = (unsigned)__shfl((int)my_pref, leader, 64);
            k = __shfl(my_k, leader, 64);
        }

        unsigned vb = pref;   // bits of s[rank_lo]

        // Phase 3: derive s[rank_lo + 1] if needed (one register pass + reduce)
        if (rank_hi != rank_lo) {                      // block-uniform
            int c = 0;
            unsigned mg = 0xFFFFFFFFu;
            #pragma unroll
            for (int j = 0; j < 8; ++j) {
                unsigned u = ub[j];
                if ((int)u >= 0) {
                    if (u <= vb) c++;
                    else mg = min(mg, u);
                }
            }
            #pragma unroll
            for (int off = 32; off > 0; off >>= 1) {
                c += __shfl_xor(c, off, 64);
                mg = min(mg, (unsigned)__shfl_xor((int)mg, off, 64));
            }
            if (lane == 0) {
                atomicAdd(&cLE_sh, c);
                atomicMin(&minGT_sh, mg);
            }
            __syncthreads();                           // S5
            float vlo = __uint_as_float(vb);
            float vhi = (cLE_sh >= rank_lo + 2) ? vlo : __uint_as_float(minGT_sh);
            float frac = pos - (float)lo;
            thr = vlo * (1.0f - frac) + vhi * frac;    // identical fp32 ops all threads
        } else {
            float vlo = __uint_as_float(vb);
            float frac = pos - (float)lo;
            thr = vlo * (1.0f - frac) + vlo * frac;    // matches reference exactly
        }
    } else {
        thr = 0.01f;
    }

    // Phase 5: mask bit-words straight from registers; zero S/E markers.
    // Thread layout t = 64*wv + lane + 512*i -> word (wv + 8i), bit = lane.
    #pragma unroll
    for (int i = 0; i < 8; ++i) {
        unsigned u = ub[i];
        bool pm = ((int)u >= 0) && (__uint_as_float(u) > thr);
        unsigned long long bm = __ballot(pm);
        int wi = wv + (i << 3);
        if (lane == 0 && wi < NWORDS) mw[wi] = bm;
    }
    if (tid < NWORDS) { Sw[tid] = 0ull; Ew[tid] = 0ull; }
    __syncthreads();                                   // S6

    // Phases 6-10: single wave, shuffle-based, no internal barriers.
    if (wv == 0) {
        int l = lane;
        unsigned long long W  = (l < NWORDS) ? mw[l] : 0ull;
        unsigned long long Wm = __shfl_up(W, 1, 64);   if (l == 0) Wm = 0ull;
        unsigned long long Wp = __shfl_down(W, 1, 64); // l>=NWORDS-1 sees W=0 neighbors

        // 18-bit window ORs across the (Wm:W:Wp) 192-bit view
        unsigned long long pa = 0ull, na = 0ull;
        #pragma unroll
        for (int d = 1; d <= SILENCE_FRAMES; ++d) {
            pa |= (W << d) | (Wm >> (64 - d));
            na |= (W >> d) | (Wp << (64 - d));
        }
        unsigned long long sWr = W & ~pa;              // segment starts
        unsigned long long lWr = W & ~na;              // segment last-ones

        // packed popcount scan (starts | lasts<<16), totals < 2^16
        int cS = __popcll(sWr), cL = __popcll(lWr);
        int packc = cS | (cL << 16);
        int incp = packc;
        #pragma unroll
        for (int off = 1; off < 64; off <<= 1) {
            int y = __shfl_up(incp, off, 64);
            if (l >= off) incp += y;
        }
        int exS = (incp & 0xFFFF) - cS;
        int exL = (incp >> 16) - cL;
        int nseg = __shfl(incp, 63) & 0xFFFF;

        // scatter ordered start/last positions (in-wave, compiler orders LDS)
        unsigned long long w1 = sWr; int idx = exS;
        while (w1) { int bit = (int)__ffsll((long long)w1) - 1;
                     startpos[idx++] = (l << 6) + bit; w1 &= w1 - 1ull; }
        unsigned long long w2 = lWr; idx = exL;
        while (w2) { int bit = (int)__ffsll((long long)w2) - 1;
                     lastpos[idx++] = (l << 6) + bit; w2 &= w2 - 1ull; }

        // per segment: end = L (closed) or n (open); validity; S/E markers
        for (int kk = l; kk < nseg; kk += 64) {
            int s = startpos[kk], L = lastpos[kk];
            int e = (L >= NFRAMES - SILENCE_FRAMES) ? NFRAMES : L;
            if (e - s >= MIN_SPEECH_FRAMES) {
                atomicOr(&Sw[s >> 6], 1ull << (s & 63));
                atomicOr(&Ew[e >> 6], 1ull << (e & 63));
            }
        }

        // packed prefix counts of S/E markers
        unsigned long long S2 = (l < NWORDS) ? Sw[l] : 0ull;
        unsigned long long E2 = (l < NWORDS) ? Ew[l] : 0ull;
        int c2 = __popcll(S2) | (__popcll(E2) << 16);
        int inc2 = c2;
        #pragma unroll
        for (int off = 1; off < 64; off <<= 1) {
            int y = __shfl_up(inc2, off, 64);
            if (l >= off) inc2 += y;
        }
        int ex2 = inc2 - c2;
        if (l < NWORDS) { wbS[l] = ex2 & 0xFFFF; wbL[l] = ex2 >> 16; }
    }
    __syncthreads();                                   // S7

    // Phase 11: coverage = (#starts <= t) > (#ends <= t); int32 output, all waves
    int* orow = out + (size_t)b * NFRAMES;
    for (int wi = wv; wi < NWORDS; wi += 8) {
        unsigned long long wS2 = Sw[wi], wE2 = Ew[wi];
        int t = (wi << 6) + lane;
        unsigned long long ile = (lane == 63) ? ~0ull : ((1ull << (lane + 1)) - 1ull);
        int cS = wbS[wi] + __popcll(wS2 & ile);
        int cE = wbL[wi] + __popcll(wE2 & ile);
        if (t < NFRAMES) orow[t] = (cS > cE) ? 1 : 0;
    }
}

extern "C" void kernel_launch(void* const* d_in, const int* in_sizes, int n_in,
                              void* d_out, int out_size, void* d_ws, size_t ws_size,
                              hipStream_t stream) {
    const float* wav = (const float*)d_in[0];
    int* out = (int*)d_out;
    double* bs = (double*)d_ws;   // NBATCH*NBLOCKS doubles = 960 KB

    vad_block_sums<<<(NBATCH * NSAMP) / 4096, 256, 0, stream>>>(wav, bs);
    vad_finish<<<NBATCH, 512, 0, stream>>>(bs, out);
}